// Round 2
// baseline (400.655 us; speedup 1.0000x reference)
//
#include <hip/hip_runtime.h>

// self_attention: B=4, C=512, C8=64, N=64*64=4096
// R8: k_attn re-tiled for L2 residency. R7 post-mortem: binding resource is
// L2/L3->CU data delivery (R7 doubled waves+VMEM dup -> 18% slower). R6 read
// 1.28 GB/dispatch (each block: full 4MB hvf + 1MB ff per batch); per-XCD hot
// set 5MB > 4MB L2 -> L3 thrash at ~9.5 TB/s = the 134us wall.
// R8: j-tile 128 x c-half 256, grid 256 x 512thr (8 waves, 2/SIMD).
//   - hvf per block 2MB -> total 512MB (halved)
//   - XCD pin: combo=L&7=(b,ch); 32 blocks/combo share hvf 2MB + ff 1MB = 3MB
//     < 4MB L2 -> re-reads are L2 hits.
//   - S computed once per c-half (2x S MFMA, +27% total MFMA - pipe is at 29%).
//   - per-wave VMEM/iter stays 12 (R7's lesson: do not grow this).
// S roles: iq2=w&1 (32 i) x jq=w>>1 (32 j) -> 24 MFMA/wave-iter.
// PV roles: wave owns 32-c strip (ch*256 + w*32), all 128 j -> 32 MFMA/wave-iter.
// P^T [128 j][64 i] LDS (stride 72), dbuf, 1 barrier/iter, 36.9 KB.

#define Bq 4
#define Cq 512
#define Nq 4096
#define PSTR 72   // P^T row stride in shorts (144 B = 9*16 -> b128-aligned rows)

typedef __attribute__((ext_vector_type(8))) short bf16x8;
typedef __attribute__((ext_vector_type(4))) float f32x4;

__device__ __forceinline__ short f2bf(float f) {
  unsigned u = __float_as_uint(f);
  u += 0x7fffu + ((u >> 16) & 1u);   // RNE
  return (short)(u >> 16);
}
__device__ __forceinline__ float bf2f(short h) {
  return __uint_as_float(((unsigned)(unsigned short)h) << 16);
}

#define MFMA16(A, B, C) __builtin_amdgcn_mfma_f32_16x16x32_bf16((A), (B), (C), 0, 0, 0)

// frag base (in shorts) for f/g token-tile t16 (16 tokens), k-chunk ss (32 of 64)
__device__ __forceinline__ size_t fg_frag(int b, int t16, int ss) {
  return ((size_t)((b * 256 + t16) * 2 + ss)) * 512;
}
// frag base for hv c-tile tc (16 c), i-chunk si (32 of 4096)
__device__ __forceinline__ size_t hv_frag(int b, int tc, int si) {
  return ((size_t)((b * 32 + tc) * 128 + si)) * 512;
}

// ---------------- K_prepw: W splits ----------------
__global__ __launch_bounds__(256) void k_prepw(
    const float* __restrict__ Wf, const float* __restrict__ Wg,
    const float* __restrict__ Wh,
    short* __restrict__ whi, short* __restrict__ wlo, short* __restrict__ whb) {
  int gid = blockIdx.x * 256 + threadIdx.x;  // 0..262143
  if (gid < 128 * 512) {
    int row = gid >> 9;
    float v = (row < 64) ? Wf[gid] : Wg[gid - 32768];
    short h = f2bf(v);
    whi[gid] = h;
    wlo[gid] = f2bf(v - bf2f(h));
  }
  whb[gid] = f2bf(Wh[gid]);
}

// ---------------- K_xpose: x (B,C,N) fp32 -> XT (B,N,C) bf16 hi/lo ----------------
__global__ __launch_bounds__(256) void k_xpose(
    const float* __restrict__ x, short* __restrict__ xthi, short* __restrict__ xtlo) {
  int b = blockIdx.z, c0 = blockIdx.y * 64, n0 = blockIdx.x * 64;
  __shared__ float tile[64][65];
  int t = threadIdx.x;
  int l = t & 15, g = t >> 4;
  const float* xp = x + ((size_t)b * Cq + c0) * Nq + n0;
#pragma unroll
  for (int e = 0; e < 4; e++) {
    int cl = g + e * 16;
    float4 v = *(const float4*)(xp + (size_t)cl * Nq + l * 4);
    tile[cl][l * 4 + 0] = v.x; tile[cl][l * 4 + 1] = v.y;
    tile[cl][l * 4 + 2] = v.z; tile[cl][l * 4 + 3] = v.w;
  }
  __syncthreads();
#pragma unroll
  for (int e = 0; e < 4; e++) {
    int nl = g + e * 16;
    short hi[4], lo[4];
#pragma unroll
    for (int qq = 0; qq < 4; qq++) {
      float v = tile[l * 4 + qq][nl];
      hi[qq] = f2bf(v);
      lo[qq] = f2bf(v - bf2f(hi[qq]));
    }
    size_t off = ((size_t)b * Nq + n0 + nl) * Cq + c0 + l * 4;
    *(short4*)(xthi + off) = make_short4(hi[0], hi[1], hi[2], hi[3]);
    *(short4*)(xtlo + off) = make_short4(lo[0], lo[1], lo[2], lo[3]);
  }
}

// ---------------- K_fg: f,g GEMM -> frag-packed stores ----------------
__global__ __launch_bounds__(512) void k_fg(
    const short* __restrict__ xthi, const short* __restrict__ xtlo,
    const short* __restrict__ whi, const short* __restrict__ wlo,
    const float* __restrict__ bfv, const float* __restrict__ bgv,
    short* __restrict__ ffh, short* __restrict__ ffl,
    short* __restrict__ gfh, short* __restrict__ gfl) {
  int b = blockIdx.y, n0 = blockIdx.x * 64;
  int t = threadIdx.x, w = t >> 6, lane = t & 63, l15 = lane & 15, q = lane >> 4;
  int wr = w & 3, wh = w >> 2;  // row group / o-half (0=f,1=g)
  const short* ah = xthi + ((size_t)b * Nq + n0 + wr * 16 + l15) * Cq;
  const short* al = xtlo + ((size_t)b * Nq + n0 + wr * 16 + l15) * Cq;
  f32x4 z = {0.f, 0.f, 0.f, 0.f};
  f32x4 acc[4] = {z, z, z, z};
  for (int ks = 0; ks < 16; ks++) {
    bf16x8 Ahi = *(const bf16x8*)(ah + ks * 32 + q * 8);
    bf16x8 Alo = *(const bf16x8*)(al + ks * 32 + q * 8);
#pragma unroll
    for (int os = 0; os < 4; os++) {
      int o = wh * 64 + os * 16 + l15;
      bf16x8 Bhi = *(const bf16x8*)(whi + o * 512 + ks * 32 + q * 8);
      bf16x8 Blo = *(const bf16x8*)(wlo + o * 512 + ks * 32 + q * 8);
      acc[os] = MFMA16(Alo, Bhi, acc[os]);
      acc[os] = MFMA16(Ahi, Blo, acc[os]);
      acc[os] = MFMA16(Ahi, Bhi, acc[os]);
    }
  }
#pragma unroll
  for (int os = 0; os < 4; os++) {
#pragma unroll
    for (int r = 0; r < 4; r++) {
      int o = os * 16 + l15;                 // 0..63 within f or g
      int n = n0 + wr * 16 + q * 4 + r;
      float v = acc[os][r] + (wh == 0 ? bfv[o] : bgv[o]);
      size_t off = ((size_t)((b * 256 + (n >> 4)) * 2 + (o >> 5))) * 512
                 + (((o >> 3) & 3) * 16 + (n & 15)) * 8 + (o & 7);
      short h = f2bf(v);
      short lo = f2bf(v - bf2f(h));
      if (wh == 0) { ffh[off] = h; ffl[off] = lo; }
      else         { gfh[off] = h; gfl[off] = lo; }
    }
  }
}

// ---------------- K_stats: partial l_i = sum_j exp(S) over a 1024-j chunk ----
// Writes per-chunk partial sums to lsum4[chunk][b][i] (no atomics).
__global__ __launch_bounds__(512) void k_stats(
    const short* __restrict__ ffh, const short* __restrict__ ffl,
    const short* __restrict__ gfh, const short* __restrict__ gfl,
    float* __restrict__ lsum4) {
  int jch = blockIdx.x, jc = jch * 1024, i0 = blockIdx.y * 64, b = blockIdx.z;
  int t = threadIdx.x, w = t >> 6, lane = t & 63, l15 = lane & 15, q = lane >> 4;
  bf16x8 Ahi[4][2], Alo[4][2];
#pragma unroll
  for (int ig = 0; ig < 4; ig++)
#pragma unroll
    for (int ss = 0; ss < 2; ss++) {
      size_t base = fg_frag(b, (i0 >> 4) + ig, ss) + lane * 8;
      Ahi[ig][ss] = *(const bf16x8*)(ffh + base);
      Alo[ig][ss] = *(const bf16x8*)(ffl + base);
    }
  float ls[16];
#pragma unroll
  for (int a = 0; a < 16; a++) ls[a] = 0.f;
  f32x4 z = {0.f, 0.f, 0.f, 0.f};
  for (int jt = 0; jt < 8; jt++) {
    int tj = (jc >> 4) + w * 8 + jt;
    bf16x8 GBh[2], GBl[2];
#pragma unroll
    for (int ss = 0; ss < 2; ss++) {
      size_t base = fg_frag(b, tj, ss) + lane * 8;
      GBh[ss] = *(const bf16x8*)(gfh + base);
      GBl[ss] = *(const bf16x8*)(gfl + base);
    }
#pragma unroll
    for (int ig = 0; ig < 4; ig++) {
      f32x4 sh = z, sl = z;
#pragma unroll
      for (int ss = 0; ss < 2; ss++) {
        sl = MFMA16(Alo[ig][ss], GBh[ss], sl);
        sl = MFMA16(Ahi[ig][ss], GBl[ss], sl);
        sh = MFMA16(Ahi[ig][ss], GBh[ss], sh);
      }
#pragma unroll
      for (int r = 0; r < 4; r++) ls[ig * 4 + r] += __expf(sh[r] + sl[r]);
    }
  }
#pragma unroll
  for (int m = 1; m < 16; m <<= 1) {
#pragma unroll
    for (int a = 0; a < 16; a++) ls[a] += __shfl_xor(ls[a], m, 64);
  }
  __shared__ float part[8][64];
  if (l15 == 0) {
#pragma unroll
    for (int ig = 0; ig < 4; ig++)
#pragma unroll
      for (int r = 0; r < 4; r++) part[w][ig * 16 + q * 4 + r] = ls[ig * 4 + r];
  }
  __syncthreads();
  if (t < 64) {
    float s = 0.f;
#pragma unroll
    for (int ww = 0; ww < 8; ww++) s += part[ww][t];
    lsum4[(size_t)jch * 16384 + (size_t)b * Nq + i0 + t] = s;
  }
}

// ---------------- K_hv: hvfrag = frag-packed bf16((Wh.x + bh)/l) ----------------
__global__ __launch_bounds__(512) void k_hv(
    const short* __restrict__ whb, const short* __restrict__ xthi,
    const float* __restrict__ bhv, const float* __restrict__ lsum4,
    short* __restrict__ hvf) {
  int si = blockIdx.x, b = blockIdx.y;
  int t = threadIdx.x, w = t >> 6, lane = t & 63, l15 = lane & 15, q = lane >> 4;
  int c0 = w * 64;
  const short* ar0 = xthi + ((size_t)b * Nq + si * 32 + l15) * Cq;
  const short* ar1 = ar0 + 16 * Cq;
  f32x4 z = {0.f, 0.f, 0.f, 0.f};
  f32x4 acc[2][4];
#pragma unroll
  for (int a = 0; a < 2; a++)
#pragma unroll
    for (int c = 0; c < 4; c++) acc[a][c] = z;
  for (int ks = 0; ks < 16; ks++) {
    bf16x8 A0 = *(const bf16x8*)(ar0 + ks * 32 + q * 8);
    bf16x8 A1 = *(const bf16x8*)(ar1 + ks * 32 + q * 8);
#pragma unroll
    for (int ct = 0; ct < 4; ct++) {
      bf16x8 Bv = *(const bf16x8*)(whb + (size_t)(c0 + ct * 16 + l15) * 512 + ks * 32 + q * 8);
      acc[0][ct] = MFMA16(A0, Bv, acc[0][ct]);
      acc[1][ct] = MFMA16(A1, Bv, acc[1][ct]);
    }
  }
  float li[2][4];
#pragma unroll
  for (int it = 0; it < 2; it++)
#pragma unroll
    for (int r = 0; r < 4; r++) {
      size_t idx = (size_t)b * Nq + si * 32 + it * 16 + q * 4 + r;
      float s = lsum4[idx] + lsum4[16384 + idx] + lsum4[32768 + idx] + lsum4[49152 + idx];
      li[it][r] = 1.0f / s;
    }
  int src0 = ((q & 1) << 5) + l15;
  int src1 = src0 + 16;
  int hiSel = q >> 1;
#pragma unroll
  for (int ct = 0; ct < 4; ct++) {
    float bias = bhv[c0 + ct * 16 + l15];
    unsigned u01[2], u23[2];
#pragma unroll
    for (int it = 0; it < 2; it++) {
      float v0 = (acc[it][ct][0] + bias) * li[it][0];
      float v1 = (acc[it][ct][1] + bias) * li[it][1];
      float v2 = (acc[it][ct][2] + bias) * li[it][2];
      float v3 = (acc[it][ct][3] + bias) * li[it][3];
      u01[it] = (unsigned)(unsigned short)f2bf(v0) | ((unsigned)(unsigned short)f2bf(v1) << 16);
      u23[it] = (unsigned)(unsigned short)f2bf(v2) | ((unsigned)(unsigned short)f2bf(v3) << 16);
    }
    unsigned a0 = __shfl((int)u01[0], src0), b0 = __shfl((int)u01[1], src0);
    unsigned a1 = __shfl((int)u23[0], src0), b1 = __shfl((int)u23[1], src0);
    unsigned a2 = __shfl((int)u01[0], src1), b2 = __shfl((int)u01[1], src1);
    unsigned a3 = __shfl((int)u23[0], src1), b3 = __shfl((int)u23[1], src1);
    uint4 st;
    st.x = hiSel ? b0 : a0;
    st.y = hiSel ? b1 : a1;
    st.z = hiSel ? b2 : a2;
    st.w = hiSel ? b3 : a3;
    *(uint4*)(hvf + hv_frag(b, (c0 >> 4) + ct, si) + (size_t)lane * 8) = st;
  }
}

// ---------------- K_attn: out = gamma * hv2 @ exp(S) + x ----------------
// 256 blocks = (b 4) x (c-half 2) x (j128-tile 32). combo = L&7 = (b,ch) pins
// each combo's 32 blocks to one XCD (round-robin dispatch) -> hvf 2MB + ff 1MB
// hot set resident in that XCD's 4MB L2.
// 512 thr, 8 waves. S roles: iq2=w&1 (32 i) x jq=w>>1 (32 j): 24 MFMA/wave-iter.
// PV roles: wave owns 32-c strip, all 128 j: 32 MFMA/wave-iter.
// P^T [128 j][64 i] in LDS (stride 72), dbuf, 1 barrier/iter.
__global__ __launch_bounds__(512, 2) void k_attn(
    const short* __restrict__ ffh, const short* __restrict__ ffl,
    const short* __restrict__ gfh, const short* __restrict__ gfl,
    const short* __restrict__ hvf, const float* __restrict__ x,
    const float* __restrict__ gp, float* __restrict__ out) {
  int L = blockIdx.x;
  int combo = L & 7;                      // -> XCD id under round-robin dispatch
  int b = combo >> 1, ch = combo & 1;     // batch, c-half
  int j0 = (L >> 3) << 7;                 // 128-j tile origin
  int t = threadIdx.x, w = t >> 6, lane = t & 63, l15 = lane & 15, q = lane >> 4;
  int iq2 = w & 1, jq = w >> 1;           // S roles: 2 i-halves x 4 j-quarters
  __shared__ __align__(16) short pt[2][128 * PSTR];   // 36.9 KB
  float gamma = gp[0];
  f32x4 z = {0.f, 0.f, 0.f, 0.f};
  f32x4 acc[2][8];                        // [ctl][jt]
#pragma unroll
  for (int a = 0; a < 2; a++)
#pragma unroll
    for (int bb = 0; bb < 8; bb++) acc[a][bb] = z;
  // Hoist g frags for this wave's S j-quarter (32 j = 2 tiles of 16).
  bf16x8 GBh[2][2], GBl[2][2];
#pragma unroll
  for (int jt = 0; jt < 2; jt++)
#pragma unroll
    for (int ss = 0; ss < 2; ss++) {
      size_t base = fg_frag(b, (j0 >> 4) + jq * 2 + jt, ss) + lane * 8;
      GBh[jt][ss] = *(const bf16x8*)(gfh + base);
      GBl[jt][ss] = *(const bf16x8*)(gfl + base);
    }

  auto computeS = [&](int it, int buf) {
#pragma unroll
    for (int itl = 0; itl < 2; itl++) {
      bf16x8 Ah[2], Al[2];
#pragma unroll
      for (int ss = 0; ss < 2; ss++) {
        size_t base = fg_frag(b, it * 4 + iq2 * 2 + itl, ss) + lane * 8;
        Ah[ss] = *(const bf16x8*)(ffh + base);
        Al[ss] = *(const bf16x8*)(ffl + base);
      }
#pragma unroll
      for (int jt = 0; jt < 2; jt++) {
        f32x4 sh = z, sl = z;
#pragma unroll
        for (int ss = 0; ss < 2; ss++) {
          sl = MFMA16(Al[ss], GBh[jt][ss], sl);
          sl = MFMA16(Ah[ss], GBl[jt][ss], sl);
          sh = MFMA16(Ah[ss], GBh[jt][ss], sh);
        }
        unsigned p01 = (unsigned)(unsigned short)f2bf(__expf(sh[0] + sl[0])) |
                       ((unsigned)(unsigned short)f2bf(__expf(sh[1] + sl[1])) << 16);
        unsigned p23 = (unsigned)(unsigned short)f2bf(__expf(sh[2] + sl[2])) |
                       ((unsigned)(unsigned short)f2bf(__expf(sh[3] + sl[3])) << 16);
        uint2 pv; pv.x = p01; pv.y = p23;
        *(uint2*)(&pt[buf][(jq * 32 + jt * 16 + l15) * PSTR +
                           iq2 * 32 + itl * 16 + q * 4]) = pv;
      }
    }
  };

  computeS(0, 0);
  for (int it = 0; it < 64; it++) {
    __syncthreads();
    int buf = it & 1;
    if (it < 63) computeS(it + 1, 1 - buf);
#pragma unroll
    for (int ss = 0; ss < 2; ss++) {
      bf16x8 PB[8];
#pragma unroll
      for (int jt = 0; jt < 8; jt++)
        PB[jt] = *(const bf16x8*)(&pt[buf][(jt * 16 + l15) * PSTR + ss * 32 + q * 8]);
#pragma unroll
      for (int ctl = 0; ctl < 2; ctl++) {
        size_t hb = hv_frag(b, ch * 16 + w * 2 + ctl, it * 2 + ss) + lane * 8;
        bf16x8 A = *(const bf16x8*)(hvf + hb);
#pragma unroll
        for (int jt = 0; jt < 8; jt++)
          acc[ctl][jt] = MFMA16(A, PB[jt], acc[ctl][jt]);
      }
    }
  }
#pragma unroll
  for (int ctl = 0; ctl < 2; ctl++) {
#pragma unroll
    for (int jt = 0; jt < 8; jt++) {
#pragma unroll
      for (int r = 0; r < 4; r++) {
        int c = ch * 256 + w * 32 + ctl * 16 + q * 4 + r;
        int j = j0 + jt * 16 + l15;
        size_t off = ((size_t)b * Cq + c) * Nq + j;
        out[off] = gamma * acc[ctl][jt][r] + x[off];
      }
    }
  }
}

extern "C" void kernel_launch(void* const* d_in, const int* in_sizes, int n_in,
                              void* d_out, int out_size, void* d_ws, size_t ws_size,
                              hipStream_t stream) {
  (void)in_sizes; (void)n_in; (void)out_size; (void)ws_size;
  const float* x  = (const float*)d_in[0];
  const float* Wf = (const float*)d_in[1];
  const float* bf = (const float*)d_in[2];
  const float* Wg = (const float*)d_in[3];
  const float* bg = (const float*)d_in[4];
  const float* Wh = (const float*)d_in[5];
  const float* bh = (const float*)d_in[6];
  const float* gm = (const float*)d_in[7];
  float* out = (float*)d_out;
  char* ws = (char*)d_ws;
  // Workspace layout (bytes); total 59,768,832 (~57 MB)
  short* xthi  = (short*)(ws);               // 16,777,216  (B,N,C) bf16 hi
  short* xtlo  = (short*)(ws + 16777216);    // 16,777,216  lo
  short* ffh   = (short*)(ws + 33554432);    //  2,097,152  f frag-packed hi
  short* ffl   = (short*)(ws + 35651584);    //  2,097,152  f lo
  short* gfh   = (short*)(ws + 37748736);    //  2,097,152  g frag-packed hi
  short* gfl   = (short*)(ws + 39845888);    //  2,097,152  g lo
  short* whi   = (short*)(ws + 41943040);    //    131,072  (128,512)
  short* wlo   = (short*)(ws + 42074112);    //    131,072
  short* whb   = (short*)(ws + 42205184);    //    524,288  (512,512)
  float* lsum4 = (float*)(ws + 42729472);    //    262,144  (4 chunks, B, N)
  short* hvf   = (short*)(ws + 42991616);    // 16,777,216  hv frag-packed bf16

  hipLaunchKernelGGL(k_prepw, dim3(1024), dim3(256), 0, stream, Wf, Wg, Wh, whi, wlo, whb);
  hipLaunchKernelGGL(k_xpose, dim3(64, 8, 4), dim3(256), 0, stream, x, xthi, xtlo);
  hipLaunchKernelGGL(k_fg, dim3(64, 4), dim3(512), 0, stream,
                     xthi, xtlo, whi, wlo, bf, bg, ffh, ffl, gfh, gfl);
  hipLaunchKernelGGL(k_stats, dim3(4, 64, 4), dim3(512), 0, stream, ffh, ffl, gfh, gfl, lsum4);
  hipLaunchKernelGGL(k_hv, dim3(128, 4), dim3(512), 0, stream, whb, xthi, bh, lsum4, hvf);
  hipLaunchKernelGGL(k_attn, dim3(256), dim3(512), 0, stream,
                     ffh, ffl, gfh, gfl, hvf, x, gm, out);
}

// Round 3
// 308.491 us; speedup vs baseline: 1.2988x; 1.2988x over previous
//
#include <hip/hip_runtime.h>

// self_attention: B=4, C=512, C8=64, N=64*64=4096
// R9: revert to R6 tiling (j-tile 64, full C, 256 blk x 512 thr, 18.4KB LDS).
// R7/R8 post-mortem: R6 is LATENCY-bound on the per-iter critical path
// (occupancy grid-limited at 1 blk/CU; delivery ~11.7 TB/s < ~20 ceiling;
// R8's longer serial chain -> slower). Fix = ILP, not TLP, not fewer bytes:
//   (a) ff(it+1) + hvf(it) loads issue BEFORE the barrier into regs -> in
//       flight across it (T14 issue-early / consume-late).
//   (b) raw s_barrier with lgkmcnt(0)-only drain (pt visibility needs only
//       LDS-write drain); no vmcnt(0) drain at the barrier (m233 stall).
//   (c) computeS consumes pre-loaded register frags.
// S roles: iq=w&3 x jh=w>>2 -> 12 MFMA/wave-iter. PV: wave owns 64-c strip,
// all 64 j -> 32 MFMA/wave-iter. P^T [64j][64i] LDS stride 72, dbuf.

#define Bq 4
#define Cq 512
#define Nq 4096
#define PSTR 72   // P^T row stride in shorts (144 B = 9*16 -> b128-aligned rows)

typedef __attribute__((ext_vector_type(8))) short bf16x8;
typedef __attribute__((ext_vector_type(4))) float f32x4;

__device__ __forceinline__ short f2bf(float f) {
  unsigned u = __float_as_uint(f);
  u += 0x7fffu + ((u >> 16) & 1u);   // RNE
  return (short)(u >> 16);
}
__device__ __forceinline__ float bf2f(short h) {
  return __uint_as_float(((unsigned)(unsigned short)h) << 16);
}

#define MFMA16(A, B, C) __builtin_amdgcn_mfma_f32_16x16x32_bf16((A), (B), (C), 0, 0, 0)

// frag base (in shorts) for f/g token-tile t16 (16 tokens), k-chunk ss (32 of 64)
__device__ __forceinline__ size_t fg_frag(int b, int t16, int ss) {
  return ((size_t)((b * 256 + t16) * 2 + ss)) * 512;
}
// frag base for hv c-tile tc (16 c), i-chunk si (32 of 4096)
__device__ __forceinline__ size_t hv_frag(int b, int tc, int si) {
  return ((size_t)((b * 32 + tc) * 128 + si)) * 512;
}

// ---------------- K_prepw: W splits ----------------
__global__ __launch_bounds__(256) void k_prepw(
    const float* __restrict__ Wf, const float* __restrict__ Wg,
    const float* __restrict__ Wh,
    short* __restrict__ whi, short* __restrict__ wlo, short* __restrict__ whb) {
  int gid = blockIdx.x * 256 + threadIdx.x;  // 0..262143
  if (gid < 128 * 512) {
    int row = gid >> 9;
    float v = (row < 64) ? Wf[gid] : Wg[gid - 32768];
    short h = f2bf(v);
    whi[gid] = h;
    wlo[gid] = f2bf(v - bf2f(h));
  }
  whb[gid] = f2bf(Wh[gid]);
}

// ---------------- K_xpose: x (B,C,N) fp32 -> XT (B,N,C) bf16 hi/lo ----------------
__global__ __launch_bounds__(256) void k_xpose(
    const float* __restrict__ x, short* __restrict__ xthi, short* __restrict__ xtlo) {
  int b = blockIdx.z, c0 = blockIdx.y * 64, n0 = blockIdx.x * 64;
  __shared__ float tile[64][65];
  int t = threadIdx.x;
  int l = t & 15, g = t >> 4;
  const float* xp = x + ((size_t)b * Cq + c0) * Nq + n0;
#pragma unroll
  for (int e = 0; e < 4; e++) {
    int cl = g + e * 16;
    float4 v = *(const float4*)(xp + (size_t)cl * Nq + l * 4);
    tile[cl][l * 4 + 0] = v.x; tile[cl][l * 4 + 1] = v.y;
    tile[cl][l * 4 + 2] = v.z; tile[cl][l * 4 + 3] = v.w;
  }
  __syncthreads();
#pragma unroll
  for (int e = 0; e < 4; e++) {
    int nl = g + e * 16;
    short hi[4], lo[4];
#pragma unroll
    for (int qq = 0; qq < 4; qq++) {
      float v = tile[l * 4 + qq][nl];
      hi[qq] = f2bf(v);
      lo[qq] = f2bf(v - bf2f(hi[qq]));
    }
    size_t off = ((size_t)b * Nq + n0 + nl) * Cq + c0 + l * 4;
    *(short4*)(xthi + off) = make_short4(hi[0], hi[1], hi[2], hi[3]);
    *(short4*)(xtlo + off) = make_short4(lo[0], lo[1], lo[2], lo[3]);
  }
}

// ---------------- K_fg: f,g GEMM -> frag-packed stores ----------------
__global__ __launch_bounds__(512) void k_fg(
    const short* __restrict__ xthi, const short* __restrict__ xtlo,
    const short* __restrict__ whi, const short* __restrict__ wlo,
    const float* __restrict__ bfv, const float* __restrict__ bgv,
    short* __restrict__ ffh, short* __restrict__ ffl,
    short* __restrict__ gfh, short* __restrict__ gfl) {
  int b = blockIdx.y, n0 = blockIdx.x * 64;
  int t = threadIdx.x, w = t >> 6, lane = t & 63, l15 = lane & 15, q = lane >> 4;
  int wr = w & 3, wh = w >> 2;  // row group / o-half (0=f,1=g)
  const short* ah = xthi + ((size_t)b * Nq + n0 + wr * 16 + l15) * Cq;
  const short* al = xtlo + ((size_t)b * Nq + n0 + wr * 16 + l15) * Cq;
  f32x4 z = {0.f, 0.f, 0.f, 0.f};
  f32x4 acc[4] = {z, z, z, z};
  for (int ks = 0; ks < 16; ks++) {
    bf16x8 Ahi = *(const bf16x8*)(ah + ks * 32 + q * 8);
    bf16x8 Alo = *(const bf16x8*)(al + ks * 32 + q * 8);
#pragma unroll
    for (int os = 0; os < 4; os++) {
      int o = wh * 64 + os * 16 + l15;
      bf16x8 Bhi = *(const bf16x8*)(whi + o * 512 + ks * 32 + q * 8);
      bf16x8 Blo = *(const bf16x8*)(wlo + o * 512 + ks * 32 + q * 8);
      acc[os] = MFMA16(Alo, Bhi, acc[os]);
      acc[os] = MFMA16(Ahi, Blo, acc[os]);
      acc[os] = MFMA16(Ahi, Bhi, acc[os]);
    }
  }
#pragma unroll
  for (int os = 0; os < 4; os++) {
#pragma unroll
    for (int r = 0; r < 4; r++) {
      int o = os * 16 + l15;                 // 0..63 within f or g
      int n = n0 + wr * 16 + q * 4 + r;
      float v = acc[os][r] + (wh == 0 ? bfv[o] : bgv[o]);
      size_t off = ((size_t)((b * 256 + (n >> 4)) * 2 + (o >> 5))) * 512
                 + (((o >> 3) & 3) * 16 + (n & 15)) * 8 + (o & 7);
      short h = f2bf(v);
      short lo = f2bf(v - bf2f(h));
      if (wh == 0) { ffh[off] = h; ffl[off] = lo; }
      else         { gfh[off] = h; gfl[off] = lo; }
    }
  }
}

// ---------------- K_stats: partial l_i = sum_j exp(S) over a 1024-j chunk ----
// Writes per-chunk partial sums to lsum4[chunk][b][i] (no atomics).
__global__ __launch_bounds__(512) void k_stats(
    const short* __restrict__ ffh, const short* __restrict__ ffl,
    const short* __restrict__ gfh, const short* __restrict__ gfl,
    float* __restrict__ lsum4) {
  int jch = blockIdx.x, jc = jch * 1024, i0 = blockIdx.y * 64, b = blockIdx.z;
  int t = threadIdx.x, w = t >> 6, lane = t & 63, l15 = lane & 15, q = lane >> 4;
  bf16x8 Ahi[4][2], Alo[4][2];
#pragma unroll
  for (int ig = 0; ig < 4; ig++)
#pragma unroll
    for (int ss = 0; ss < 2; ss++) {
      size_t base = fg_frag(b, (i0 >> 4) + ig, ss) + lane * 8;
      Ahi[ig][ss] = *(const bf16x8*)(ffh + base);
      Alo[ig][ss] = *(const bf16x8*)(ffl + base);
    }
  float ls[16];
#pragma unroll
  for (int a = 0; a < 16; a++) ls[a] = 0.f;
  f32x4 z = {0.f, 0.f, 0.f, 0.f};
  for (int jt = 0; jt < 8; jt++) {
    int tj = (jc >> 4) + w * 8 + jt;
    bf16x8 GBh[2], GBl[2];
#pragma unroll
    for (int ss = 0; ss < 2; ss++) {
      size_t base = fg_frag(b, tj, ss) + lane * 8;
      GBh[ss] = *(const bf16x8*)(gfh + base);
      GBl[ss] = *(const bf16x8*)(gfl + base);
    }
#pragma unroll
    for (int ig = 0; ig < 4; ig++) {
      f32x4 sh = z, sl = z;
#pragma unroll
      for (int ss = 0; ss < 2; ss++) {
        sl = MFMA16(Alo[ig][ss], GBh[ss], sl);
        sl = MFMA16(Ahi[ig][ss], GBl[ss], sl);
        sh = MFMA16(Ahi[ig][ss], GBh[ss], sh);
      }
#pragma unroll
      for (int r = 0; r < 4; r++) ls[ig * 4 + r] += __expf(sh[r] + sl[r]);
    }
  }
#pragma unroll
  for (int m = 1; m < 16; m <<= 1) {
#pragma unroll
    for (int a = 0; a < 16; a++) ls[a] += __shfl_xor(ls[a], m, 64);
  }
  __shared__ float part[8][64];
  if (l15 == 0) {
#pragma unroll
    for (int ig = 0; ig < 4; ig++)
#pragma unroll
      for (int r = 0; r < 4; r++) part[w][ig * 16 + q * 4 + r] = ls[ig * 4 + r];
  }
  __syncthreads();
  if (t < 64) {
    float s = 0.f;
#pragma unroll
    for (int ww = 0; ww < 8; ww++) s += part[ww][t];
    lsum4[(size_t)jch * 16384 + (size_t)b * Nq + i0 + t] = s;
  }
}

// ---------------- K_hv: hvfrag = frag-packed bf16((Wh.x + bh)/l) ----------------
__global__ __launch_bounds__(512) void k_hv(
    const short* __restrict__ whb, const short* __restrict__ xthi,
    const float* __restrict__ bhv, const float* __restrict__ lsum4,
    short* __restrict__ hvf) {
  int si = blockIdx.x, b = blockIdx.y;
  int t = threadIdx.x, w = t >> 6, lane = t & 63, l15 = lane & 15, q = lane >> 4;
  int c0 = w * 64;
  const short* ar0 = xthi + ((size_t)b * Nq + si * 32 + l15) * Cq;
  const short* ar1 = ar0 + 16 * Cq;
  f32x4 z = {0.f, 0.f, 0.f, 0.f};
  f32x4 acc[2][4];
#pragma unroll
  for (int a = 0; a < 2; a++)
#pragma unroll
    for (int c = 0; c < 4; c++) acc[a][c] = z;
  for (int ks = 0; ks < 16; ks++) {
    bf16x8 A0 = *(const bf16x8*)(ar0 + ks * 32 + q * 8);
    bf16x8 A1 = *(const bf16x8*)(ar1 + ks * 32 + q * 8);
#pragma unroll
    for (int ct = 0; ct < 4; ct++) {
      bf16x8 Bv = *(const bf16x8*)(whb + (size_t)(c0 + ct * 16 + l15) * 512 + ks * 32 + q * 8);
      acc[0][ct] = MFMA16(A0, Bv, acc[0][ct]);
      acc[1][ct] = MFMA16(A1, Bv, acc[1][ct]);
    }
  }
  float li[2][4];
#pragma unroll
  for (int it = 0; it < 2; it++)
#pragma unroll
    for (int r = 0; r < 4; r++) {
      size_t idx = (size_t)b * Nq + si * 32 + it * 16 + q * 4 + r;
      float s = lsum4[idx] + lsum4[16384 + idx] + lsum4[32768 + idx] + lsum4[49152 + idx];
      li[it][r] = 1.0f / s;
    }
  int src0 = ((q & 1) << 5) + l15;
  int src1 = src0 + 16;
  int hiSel = q >> 1;
#pragma unroll
  for (int ct = 0; ct < 4; ct++) {
    float bias = bhv[c0 + ct * 16 + l15];
    unsigned u01[2], u23[2];
#pragma unroll
    for (int it = 0; it < 2; it++) {
      float v0 = (acc[it][ct][0] + bias) * li[it][0];
      float v1 = (acc[it][ct][1] + bias) * li[it][1];
      float v2 = (acc[it][ct][2] + bias) * li[it][2];
      float v3 = (acc[it][ct][3] + bias) * li[it][3];
      u01[it] = (unsigned)(unsigned short)f2bf(v0) | ((unsigned)(unsigned short)f2bf(v1) << 16);
      u23[it] = (unsigned)(unsigned short)f2bf(v2) | ((unsigned)(unsigned short)f2bf(v3) << 16);
    }
    unsigned a0 = __shfl((int)u01[0], src0), b0 = __shfl((int)u01[1], src0);
    unsigned a1 = __shfl((int)u23[0], src0), b1 = __shfl((int)u23[1], src0);
    unsigned a2 = __shfl((int)u01[0], src1), b2 = __shfl((int)u01[1], src1);
    unsigned a3 = __shfl((int)u23[0], src1), b3 = __shfl((int)u23[1], src1);
    uint4 st;
    st.x = hiSel ? b0 : a0;
    st.y = hiSel ? b1 : a1;
    st.z = hiSel ? b2 : a2;
    st.w = hiSel ? b3 : a3;
    *(uint4*)(hvf + hv_frag(b, (c0 >> 4) + ct, si) + (size_t)lane * 8) = st;
  }
}

// ---------------- K_attn: out = gamma * hv2 @ exp(S) + x ----------------
// 256 blocks (b x j64), 512 thr. S roles: wave = (iq = w&3) x (jh = w>>2).
// PV roles: wave owns c-strip w*64, all 64 j. 44 MFMA/wave-iter.
// P^T [64 j][64 i] in LDS (stride 72), dbuf. Per-iter schedule:
//   [issue ff(it+1) + hvf(it) loads]  <- stay in flight across barrier
//   s_waitcnt lgkmcnt(0); s_barrier   <- LDS-write drain only, NO vmcnt drain
//   computeS(it+1) from regs -> pt[1-buf]; PV(it) from pt[buf] + HV regs
__global__ __launch_bounds__(512, 2) void k_attn(
    const short* __restrict__ ffh, const short* __restrict__ ffl,
    const short* __restrict__ gfh, const short* __restrict__ gfl,
    const short* __restrict__ hvf, const float* __restrict__ x,
    const float* __restrict__ gp, float* __restrict__ out) {
  int L = blockIdx.x;
  int b = (L & 7) >> 1;                   // batch -> XCD pair
  int jt64 = ((L >> 3) << 1) | (L & 1);   // 0..63
  int j0 = jt64 * 64;
  int t = threadIdx.x, w = t >> 6, lane = t & 63, l15 = lane & 15, q = lane >> 4;
  int iq = w & 3, jh = w >> 2;            // S roles
  __shared__ __align__(16) short pt[2][64 * PSTR];   // 18.4 KB
  float gamma = gp[0];
  f32x4 z = {0.f, 0.f, 0.f, 0.f};
  f32x4 acc[4][4];                        // [ct][jt]
#pragma unroll
  for (int a = 0; a < 4; a++)
#pragma unroll
    for (int bb = 0; bb < 4; bb++) acc[a][bb] = z;
  // Hoist g frags for this wave's S j-half (2 tiles of 16 j).
  bf16x8 GBh[2][2], GBl[2][2];
#pragma unroll
  for (int jt = 0; jt < 2; jt++)
#pragma unroll
    for (int ss = 0; ss < 2; ss++) {
      size_t base = fg_frag(b, (j0 >> 4) + jh * 2 + jt, ss) + lane * 8;
      GBh[jt][ss] = *(const bf16x8*)(gfh + base);
      GBl[jt][ss] = *(const bf16x8*)(gfl + base);
    }

  // S compute from pre-loaded register fragments.
  auto computeS = [&](const bf16x8* Ah, const bf16x8* Al, int buf) {
#pragma unroll
    for (int jt = 0; jt < 2; jt++) {
      f32x4 sh = z, sl = z;
#pragma unroll
      for (int ss = 0; ss < 2; ss++) {
        sl = MFMA16(Al[ss], GBh[jt][ss], sl);
        sl = MFMA16(Ah[ss], GBl[jt][ss], sl);
        sh = MFMA16(Ah[ss], GBh[jt][ss], sh);
      }
      unsigned p01 = (unsigned)(unsigned short)f2bf(__expf(sh[0] + sl[0])) |
                     ((unsigned)(unsigned short)f2bf(__expf(sh[1] + sl[1])) << 16);
      unsigned p23 = (unsigned)(unsigned short)f2bf(__expf(sh[2] + sl[2])) |
                     ((unsigned)(unsigned short)f2bf(__expf(sh[3] + sl[3])) << 16);
      uint2 pv; pv.x = p01; pv.y = p23;
      *(uint2*)(&pt[buf][(jh * 32 + jt * 16 + l15) * PSTR + iq * 16 + q * 4]) = pv;
    }
  };

  bf16x8 FFh[2], FFl[2];
  // Prologue: load ff(0), compute pt[0].
#pragma unroll
  for (int ss = 0; ss < 2; ss++) {
    size_t base = fg_frag(b, 0 * 4 + iq, ss) + lane * 8;
    FFh[ss] = *(const bf16x8*)(ffh + base);
    FFl[ss] = *(const bf16x8*)(ffl + base);
  }
  computeS(FFh, FFl, 0);

  for (int it = 0; it < 64; it++) {
    int buf = it & 1;
    // --- pre-barrier VMEM issue (in flight across the barrier) ---
    if (it < 63) {
#pragma unroll
      for (int ss = 0; ss < 2; ss++) {
        size_t base = fg_frag(b, (it + 1) * 4 + iq, ss) + lane * 8;
        FFh[ss] = *(const bf16x8*)(ffh + base);
        FFl[ss] = *(const bf16x8*)(ffl + base);
      }
    }
    bf16x8 HV[2][4];
#pragma unroll
    for (int ss = 0; ss < 2; ss++)
#pragma unroll
      for (int ct = 0; ct < 4; ct++) {
        size_t hb = hv_frag(b, w * 4 + ct, it * 2 + ss) + lane * 8;
        HV[ss][ct] = *(const bf16x8*)(hvf + hb);
      }
    // --- barrier: drain LDS writes only; leave VMEM in flight ---
    asm volatile("s_waitcnt lgkmcnt(0)" ::: "memory");
    __builtin_amdgcn_s_barrier();
    asm volatile("" ::: "memory");
    // --- post-barrier: S(it+1) then PV(it) ---
    if (it < 63) computeS(FFh, FFl, 1 - buf);
#pragma unroll
    for (int ss = 0; ss < 2; ss++) {
      bf16x8 PB[4];
#pragma unroll
      for (int jt = 0; jt < 4; jt++)
        PB[jt] = *(const bf16x8*)(&pt[buf][(jt * 16 + l15) * PSTR + ss * 32 + q * 8]);
#pragma unroll
      for (int ct = 0; ct < 4; ct++) {
#pragma unroll
        for (int jt = 0; jt < 4; jt++)
          acc[ct][jt] = MFMA16(HV[ss][ct], PB[jt], acc[ct][jt]);
      }
    }
  }
#pragma unroll
  for (int ct = 0; ct < 4; ct++) {
#pragma unroll
    for (int jt = 0; jt < 4; jt++) {
#pragma unroll
      for (int r = 0; r < 4; r++) {
        int c = w * 64 + ct * 16 + q * 4 + r;
        int j = j0 + jt * 16 + l15;
        size_t off = ((size_t)b * Cq + c) * Nq + j;
        out[off] = gamma * acc[ct][jt][r] + x[off];
      }
    }
  }
}

extern "C" void kernel_launch(void* const* d_in, const int* in_sizes, int n_in,
                              void* d_out, int out_size, void* d_ws, size_t ws_size,
                              hipStream_t stream) {
  (void)in_sizes; (void)n_in; (void)out_size; (void)ws_size;
  const float* x  = (const float*)d_in[0];
  const float* Wf = (const float*)d_in[1];
  const float* bf = (const float*)d_in[2];
  const float* Wg = (const float*)d_in[3];
  const float* bg = (const float*)d_in[4];
  const float* Wh = (const float*)d_in[5];
  const float* bh = (const float*)d_in[6];
  const float* gm = (const float*)d_in[7];
  float* out = (float*)d_out;
  char* ws = (char*)d_ws;
  // Workspace layout (bytes); total 59,768,832 (~57 MB)
  short* xthi  = (short*)(ws);               // 16,777,216  (B,N,C) bf16 hi
  short* xtlo  = (short*)(ws + 16777216);    // 16,777,216  lo
  short* ffh   = (short*)(ws + 33554432);    //  2,097,152  f frag-packed hi
  short* ffl   = (short*)(ws + 35651584);    //  2,097,152  f lo
  short* gfh   = (short*)(ws + 37748736);    //  2,097,152  g frag-packed hi
  short* gfl   = (short*)(ws + 39845888);    //  2,097,152  g lo
  short* whi   = (short*)(ws + 41943040);    //    131,072  (128,512)
  short* wlo   = (short*)(ws + 42074112);    //    131,072
  short* whb   = (short*)(ws + 42205184);    //    524,288  (512,512)
  float* lsum4 = (float*)(ws + 42729472);    //    262,144  (4 chunks, B, N)
  short* hvf   = (short*)(ws + 42991616);    // 16,777,216  hv frag-packed bf16

  hipLaunchKernelGGL(k_prepw, dim3(1024), dim3(256), 0, stream, Wf, Wg, Wh, whi, wlo, whb);
  hipLaunchKernelGGL(k_xpose, dim3(64, 8, 4), dim3(256), 0, stream, x, xthi, xtlo);
  hipLaunchKernelGGL(k_fg, dim3(64, 4), dim3(512), 0, stream,
                     xthi, xtlo, whi, wlo, bf, bg, ffh, ffl, gfh, gfl);
  hipLaunchKernelGGL(k_stats, dim3(4, 64, 4), dim3(512), 0, stream, ffh, ffl, gfh, gfl, lsum4);
  hipLaunchKernelGGL(k_hv, dim3(128, 4), dim3(512), 0, stream, whb, xthi, bh, lsum4, hvf);
  hipLaunchKernelGGL(k_attn, dim3(256), dim3(512), 0, stream,
                     ffh, ffl, gfh, gfl, hvf, x, gm, out);
}